// Round 13
// baseline (76.789 us; speedup 1.0000x reference)
//
#include <hip/hip_runtime.h>
#include <hip/hip_bf16.h>
#include <math.h>

// Problem dims (fixed by reference): B=64, N=32, S=1024, D=128
#define NB 64
#define NTOK 32
#define NS 1024
#define ND 128

typedef __attribute__((ext_vector_type(8))) short short8;  // 8 x bf16
typedef __attribute__((ext_vector_type(4))) float f32x4;

__device__ __forceinline__ unsigned short f2bf(float x) {
    unsigned int u = __builtin_bit_cast(unsigned int, x);
    u += 0x7fffu + ((u >> 16) & 1u);  // round-to-nearest-even
    return (unsigned short)(u >> 16);
}

// RTNE pack; used for the once-read neg inline convert (same rounding as f2bf).
__device__ __forceinline__ short8 cvt8(float4 a, float4 b) {
    union { unsigned int u[4]; short8 s; } r;
    asm("v_cvt_pk_bf16_f32 %0, %1, %2" : "=v"(r.u[0]) : "v"(a.x), "v"(a.y));
    asm("v_cvt_pk_bf16_f32 %0, %1, %2" : "=v"(r.u[1]) : "v"(a.z), "v"(a.w));
    asm("v_cvt_pk_bf16_f32 %0, %1, %2" : "=v"(r.u[2]) : "v"(b.x), "v"(b.y));
    asm("v_cvt_pk_bf16_f32 %0, %1, %2" : "=v"(r.u[3]) : "v"(b.z), "v"(b.w));
    return r.s;
}

// Convert ONLY q + doc (reused many times; neg converted inline in maxsim).
// Tile = 16x128 fp32 -> fragment layout [tile][ks(4)][lane(64)][8] bf16;
// lane l = row (l&15), k = ks*32+8*(l>>4)+j. LDS-bounced, both sides coalesced.
__global__ __launch_bounds__(256) void convert_qd(const float* __restrict__ q,
                                                  const float* __restrict__ dc,
                                                  short* __restrict__ qf,
                                                  short* __restrict__ df) {
    __shared__ short lds[2][2048];
    int t = threadIdx.x;
    int row = t >> 4, g = t & 15;
    int slot = ((g >> 2) * 64 + (g & 3) * 16 + row);
#pragma unroll
    for (int half = 0; half < 2; ++half) {
        int tile = blockIdx.x * 2 + half;  // [0,128) q | [128,4224) doc
        const float* in = (tile < 128) ? q : dc;
        int rel = (tile < 128) ? tile : tile - 128;
        const float4* src = (const float4*)(in + (size_t)rel * 2048 + t * 8);
        float4 a = src[0], b = src[1];
        float f[8] = {a.x, a.y, a.z, a.w, b.x, b.y, b.z, b.w};
        short8 r;
#pragma unroll
        for (int j = 0; j < 8; ++j) r[j] = (short)f2bf(f[j]);
        *(short8*)(&lds[half][slot * 8]) = r;
    }
    __syncthreads();
#pragma unroll
    for (int half = 0; half < 2; ++half) {
        int tile = blockIdx.x * 2 + half;
        short* out = (tile < 128) ? qf : df;
        int rel = (tile < 128) ? tile : tile - 128;
        *(short8*)(out + (size_t)rel * 2048 + t * 8) = *(const short8*)(&lds[half][t * 8]);
    }
}

// T3+T4 maxsim (R11 ring) with doubled B-reuse: wave w = (bq=w>>1, shalf=w&1)
// owns 4 b's x half the chunk (32 docs) -> per-wave LDS reads halved (1:8
// reuse), qa = 128 VGPR (LDS 64KB is the occupancy binder, VGPR free to 256).
// Grid (c=64, bg=8): XCD = c%8; 512 blocks = 2/CU. 16 chunks x 64 doc rows;
// 4-deep LDS ring; 3 chunks of DMA in flight; counted vmcnt, never 0 in
// steady state; raw s_barrier; s-halves combined in reduce_b.
__global__ __launch_bounds__(256, 2) void maxsim_main(const short* __restrict__ qf,
                                                      const short* __restrict__ df,
                                                      const float* __restrict__ ng,
                                                      float* __restrict__ score_part,
                                                      float* __restrict__ neg_part) {
    int c = blockIdx.x;
    int bg = blockIdx.y;
    int t = threadIdx.x;
    int w = t >> 6, l = t & 63;
    int bq = w >> 1, shalf = w & 1;
    int b0 = bg * 8 + bq * 4;  // this wave: b0..b0+3, s-half shalf

    __shared__ alignas(16) short lds[4][8192];  // 4 x 16KB ring
    const short* dbase = df + (size_t)c * (NS * ND);
    f32x4 zero = {0.f, 0.f, 0.f, 0.f};

    // q fragments: [bb(4)][m(2)][ks(4)] -> 128 VGPR
    short8 qa[4][2][4];
#pragma unroll
    for (int bb = 0; bb < 4; ++bb)
#pragma unroll
        for (int m = 0; m < 2; ++m)
#pragma unroll
            for (int ks = 0; ks < 4; ++ks)
                qa[bb][m][ks] =
                    *(const short8*)(qf + (((b0 + bb) * 2 + m) * 4 + ks) * 512 + l * 8);

    // fused neg partial: this wave covers 2 of its 4 b's (unique (c,b) coverage)
#pragma unroll
    for (int i = 0; i < 2; ++i) {
        int bb = shalf * 2 + i;
        const float* nt =
            ng + ((size_t)((b0 + bb) * 64 + c) * 16 + (l & 15)) * ND + 8 * (l >> 4);
        short8 nb[4];
#pragma unroll
        for (int ks = 0; ks < 4; ++ks) {
            const float* sp = nt + ks * 32;
            nb[ks] = cvt8(((const float4*)sp)[0], ((const float4*)sp)[1]);
        }
#pragma unroll
        for (int m = 0; m < 2; ++m) {
            f32x4 acc = zero;
#pragma unroll
            for (int ks = 0; ks < 4; ++ks)
                acc = __builtin_amdgcn_mfma_f32_16x16x32_bf16(qa[bb][m][ks], nb[ks], acc, 0, 0, 0);
#pragma unroll
            for (int r = 0; r < 4; ++r) {  // rowmax over s within 16-lane group
                float v = acc[r];
                v = fmaxf(v, __shfl_xor(v, 1));
                v = fmaxf(v, __shfl_xor(v, 2));
                v = fmaxf(v, __shfl_xor(v, 4));
                v = fmaxf(v, __shfl_xor(v, 8));
                if ((l & 15) == 0)
                    neg_part[(c * 64 + (b0 + bb)) * 32 + m * 16 + (l >> 4) * 4 + r] = v;
            }
        }
    }

    // Normalize vmcnt to exactly 0 so the counted scheme below is exact.
    asm volatile("s_waitcnt vmcnt(0) lgkmcnt(0)" ::: "memory");
    __builtin_amdgcn_sched_barrier(0);

    // DMA-stage chunk K into ring slot K&3: 4 issues x 16B/thread, linear.
#define STAGE(K)                                                                 \
    {                                                                            \
        const short* _s = dbase + (K) * 8192 + t * 8;                            \
        short* _d = &lds[(K) & 3][t * 8];                                        \
        _Pragma("unroll") for (int i = 0; i < 4; ++i)                            \
            __builtin_amdgcn_global_load_lds(                                    \
                (const __attribute__((address_space(1))) void*)(_s + i * 2048),  \
                (__attribute__((address_space(3))) void*)(_d + i * 2048),        \
                16, 0, 0);                                                       \
    }

    STAGE(0) STAGE(1) STAGE(2)  // 12 loads/thread in flight

    f32x4 vmax[4][2];
#pragma unroll
    for (int bb = 0; bb < 4; ++bb)
#pragma unroll
        for (int m = 0; m < 2; ++m)
#pragma unroll
            for (int r = 0; r < 4; ++r) vmax[bb][m][r] = -INFINITY;

    for (int ch = 0; ch < 16; ++ch) {
        // chunk ch resident when <= 2 chunks (8 loads) remain outstanding
        if (ch <= 13) {
            asm volatile("s_waitcnt vmcnt(8)" ::: "memory");
        } else if (ch == 14) {
            asm volatile("s_waitcnt vmcnt(4)" ::: "memory");
        } else {
            asm volatile("s_waitcnt vmcnt(0)" ::: "memory");
        }
        __builtin_amdgcn_sched_barrier(0);
        __builtin_amdgcn_s_barrier();  // chunk ch resident; slot (ch+3)&3 free
        if (ch + 3 < 16) STAGE(ch + 3)

        const short* buf = &lds[ch & 3][0];
#pragma unroll
        for (int si = 0; si < 2; ++si) {  // this wave's 2 s-subtiles (32 docs)
            int ss = shalf * 2 + si;
            short8 bf[4];
#pragma unroll
            for (int ks = 0; ks < 4; ++ks)
                bf[ks] = *(const short8*)(buf + ((ss * 4 + ks) * 64 + l) * 8);
            __builtin_amdgcn_s_setprio(1);
#pragma unroll
            for (int bb = 0; bb < 4; ++bb)
#pragma unroll
                for (int m = 0; m < 2; ++m) {
                    f32x4 acc = zero;
#pragma unroll
                    for (int ks = 0; ks < 4; ++ks)
                        acc = __builtin_amdgcn_mfma_f32_16x16x32_bf16(qa[bb][m][ks], bf[ks], acc, 0, 0, 0);
#pragma unroll
                    for (int r = 0; r < 4; ++r)
                        vmax[bb][m][r] = fmaxf(vmax[bb][m][r], acc[r]);
                }
            __builtin_amdgcn_s_setprio(0);
        }
    }
#undef STAGE

    // per-n rowmax -> score_part[((shalf*64 + c)*64 + b)*32 + n]
#pragma unroll
    for (int bb = 0; bb < 4; ++bb)
#pragma unroll
        for (int m = 0; m < 2; ++m)
#pragma unroll
            for (int r = 0; r < 4; ++r) {
                float v = vmax[bb][m][r];
                v = fmaxf(v, __shfl_xor(v, 1));
                v = fmaxf(v, __shfl_xor(v, 2));
                v = fmaxf(v, __shfl_xor(v, 4));
                v = fmaxf(v, __shfl_xor(v, 8));
                if ((l & 15) == 0)
                    score_part[((shalf * 64 + c) * 64 + (b0 + bb)) * 32 + m * 16 + (l >> 4) * 4 + r] = v;
            }
}

// Per-b: combine s-halves (elementwise max) -> scores[b][c] (c = lane),
// reduce neg over c, CE + softplus -> bloss[b]. 64 blocks x 64 threads.
__global__ __launch_bounds__(64) void reduce_b(const float* __restrict__ score_part,
                                               const float* __restrict__ neg_part,
                                               const int* __restrict__ offp,
                                               float* __restrict__ bloss) {
    int b = blockIdx.x;
    int c = threadIdx.x;  // one wave
    const float4* p0 = (const float4*)(score_part + (c * 64 + b) * 32);
    const float4* p1 = (const float4*)(score_part + 64 * 64 * 32 + (c * 64 + b) * 32);
    float s = 0.f;
#pragma unroll
    for (int j = 0; j < 8; ++j) {
        float4 a = p0[j], q = p1[j];
        s += fmaxf(a.x, q.x) + fmaxf(a.y, q.y) + fmaxf(a.z, q.z) + fmaxf(a.w, q.w);
    }
    // neg: elementwise max over c of neg_part[c][b][n], then sum over n
    float v[32];
    {
        const float4* np = (const float4*)(neg_part + (c * 64 + b) * 32);
#pragma unroll
        for (int j = 0; j < 8; ++j) {
            float4 a = np[j];
            v[j * 4] = a.x; v[j * 4 + 1] = a.y; v[j * 4 + 2] = a.z; v[j * 4 + 3] = a.w;
        }
    }
#pragma unroll
    for (int off = 1; off < 64; off <<= 1)
#pragma unroll
        for (int j = 0; j < 32; ++j) v[j] = fmaxf(v[j], __shfl_xor(v[j], off));
    float negs = 0.f;
#pragma unroll
    for (int j = 0; j < 32; ++j) negs += v[j];

    const float invT = 50.0f;
    float m = s;
#pragma unroll
    for (int off = 1; off < 64; off <<= 1) m = fmaxf(m, __shfl_xor(m, off));
    float e = expf((s - m) * invT);
#pragma unroll
    for (int off = 1; off < 64; off <<= 1) e += __shfl_xor(e, off);
    float lse = m * invT + logf(e);
    int label = offp[0] + b;
    label = label < 0 ? 0 : (label > 63 ? 63 : label);
    float slabel = __shfl(s, label);
    float pos = __shfl(s, b);
    if (c == 0) {
        float x = (negs - pos) * invT;
        float sp = fmaxf(x, 0.f) + log1pf(expf(-fabsf(x)));
        bloss[b] = sp + lse - slabel * invT;
    }
}

__global__ __launch_bounds__(64) void final_sum(const float* __restrict__ bloss,
                                                float* __restrict__ out) {
    float v = bloss[threadIdx.x];
#pragma unroll
    for (int off = 1; off < 64; off <<= 1) v += __shfl_xor(v, off);
    if (threadIdx.x == 0) out[0] = v * (0.5f / 64.f);
}

extern "C" void kernel_launch(void* const* d_in, const int* in_sizes, int n_in,
                              void* d_out, int out_size, void* d_ws, size_t ws_size,
                              hipStream_t stream) {
    const float* q = (const float*)d_in[0];
    const float* dc = (const float*)d_in[1];
    const float* ng = (const float*)d_in[2];
    const int* offp = (const int*)d_in[3];
    float* out = (float*)d_out;

    // ws: qf 512KB @0 | df 16MB @0x80000 | neg_part 512KB @0x1080000 |
    //     score_part 1MB @0x1100000 | bloss @0x1200000
    char* ws = (char*)d_ws;
    short* qf = (short*)(ws);
    short* df = (short*)(ws + 0x80000);
    float* neg_part = (float*)(ws + 0x1080000);
    float* score_part = (float*)(ws + 0x1100000);
    float* bloss = (float*)(ws + 0x1200000);
    if (ws_size < 0x1200200) return;

    convert_qd<<<2112, 256, 0, stream>>>(q, dc, qf, df);
    maxsim_main<<<dim3(64, 8), 256, 0, stream>>>(qf, df, ng, score_part, neg_part);
    reduce_b<<<64, 64, 0, stream>>>(score_part, neg_part, offp, bloss);
    final_sum<<<1, 64, 0, stream>>>(bloss, out);
}

// Round 14
// 52.614 us; speedup vs baseline: 1.4595x; 1.4595x over previous
//
#include <hip/hip_runtime.h>
#include <hip/hip_bf16.h>
#include <math.h>

// Problem dims (fixed by reference): B=64, N=32, S=1024, D=128
#define NB 64
#define NTOK 32
#define NS 1024
#define ND 128

typedef __attribute__((ext_vector_type(8))) short short8;  // 8 x bf16
typedef __attribute__((ext_vector_type(4))) float f32x4;

__device__ __forceinline__ unsigned short f2bf(float x) {
    unsigned int u = __builtin_bit_cast(unsigned int, x);
    u += 0x7fffu + ((u >> 16) & 1u);  // round-to-nearest-even
    return (unsigned short)(u >> 16);
}

// RTNE pack; used for the once-read neg inline convert (same rounding as f2bf).
__device__ __forceinline__ short8 cvt8(float4 a, float4 b) {
    union { unsigned int u[4]; short8 s; } r;
    asm("v_cvt_pk_bf16_f32 %0, %1, %2" : "=v"(r.u[0]) : "v"(a.x), "v"(a.y));
    asm("v_cvt_pk_bf16_f32 %0, %1, %2" : "=v"(r.u[1]) : "v"(a.z), "v"(a.w));
    asm("v_cvt_pk_bf16_f32 %0, %1, %2" : "=v"(r.u[2]) : "v"(b.x), "v"(b.y));
    asm("v_cvt_pk_bf16_f32 %0, %1, %2" : "=v"(r.u[3]) : "v"(b.z), "v"(b.w));
    return r.s;
}

// Convert ONLY q + doc (reused many times; neg converted inline in maxsim).
// Tile = 16x128 fp32 -> fragment layout [tile][ks(4)][lane(64)][8] bf16;
// lane l = row (l&15), k = ks*32+8*(l>>4)+j. LDS-bounced, both sides coalesced.
__global__ __launch_bounds__(256) void convert_qd(const float* __restrict__ q,
                                                  const float* __restrict__ dc,
                                                  short* __restrict__ qf,
                                                  short* __restrict__ df) {
    __shared__ short lds[2][2048];
    int t = threadIdx.x;
    int row = t >> 4, g = t & 15;
    int slot = ((g >> 2) * 64 + (g & 3) * 16 + row);
#pragma unroll
    for (int half = 0; half < 2; ++half) {
        int tile = blockIdx.x * 2 + half;  // [0,128) q | [128,4224) doc
        const float* in = (tile < 128) ? q : dc;
        int rel = (tile < 128) ? tile : tile - 128;
        const float4* src = (const float4*)(in + (size_t)rel * 2048 + t * 8);
        float4 a = src[0], b = src[1];
        float f[8] = {a.x, a.y, a.z, a.w, b.x, b.y, b.z, b.w};
        short8 r;
#pragma unroll
        for (int j = 0; j < 8; ++j) r[j] = (short)f2bf(f[j]);
        *(short8*)(&lds[half][slot * 8]) = r;
    }
    __syncthreads();
#pragma unroll
    for (int half = 0; half < 2; ++half) {
        int tile = blockIdx.x * 2 + half;
        short* out = (tile < 128) ? qf : df;
        int rel = (tile < 128) ? tile : tile - 128;
        *(short8*)(out + (size_t)rel * 2048 + t * 8) = *(const short8*)(&lds[half][t * 8]);
    }
}

// T3+T4 maxsim, block-level B-reuse doubled: 8 waves (512 thr), 16 b's/block
// (still 2 b/wave -> qa = 64 VGPR, R11's proven no-spill register shape).
// Grid (c=64, bg=4) = 256 blocks = 1/CU: per-CU MFMA + LDS reads unchanged vs
// R11, DMA bytes and barrier count per CU HALVED. XCD = c%8; 4 blocks/slice
// co-XCD. 16 chunks x 64 doc rows (16KB); 4-deep LDS ring; 3 chunks of DMA in
// flight (2 loads/thread each); counted vmcnt, never 0 in steady state.
__global__ __launch_bounds__(512, 1) void maxsim_main(const short* __restrict__ qf,
                                                      const short* __restrict__ df,
                                                      const float* __restrict__ ng,
                                                      float* __restrict__ score_part,
                                                      float* __restrict__ neg_part) {
    int c = blockIdx.x;
    int bg = blockIdx.y;
    int t = threadIdx.x;
    int w = t >> 6, l = t & 63;
    int b0 = bg * 16 + w * 2;  // this wave: b0, b0+1

    __shared__ alignas(16) short lds[4][8192];  // 4 x 16KB ring
    const short* dbase = df + (size_t)c * (NS * ND);
    f32x4 zero = {0.f, 0.f, 0.f, 0.f};

    // q fragments: [bb][mtile][kstep] -> 64 VGPR
    short8 qa[2][2][4];
#pragma unroll
    for (int bb = 0; bb < 2; ++bb)
#pragma unroll
        for (int m = 0; m < 2; ++m)
#pragma unroll
            for (int ks = 0; ks < 4; ++ks)
                qa[bb][m][ks] =
                    *(const short8*)(qf + (((b0 + bb) * 2 + m) * 4 + ks) * 512 + l * 8);

    // fused neg partial: tile (b, s-chunk c) of q[b]·neg[b], fp32 read + inline cvt
#pragma unroll
    for (int bb = 0; bb < 2; ++bb) {
        const float* nt =
            ng + ((size_t)((b0 + bb) * 64 + c) * 16 + (l & 15)) * ND + 8 * (l >> 4);
        short8 nb[4];
#pragma unroll
        for (int ks = 0; ks < 4; ++ks) {
            const float* sp = nt + ks * 32;
            nb[ks] = cvt8(((const float4*)sp)[0], ((const float4*)sp)[1]);
        }
#pragma unroll
        for (int m = 0; m < 2; ++m) {
            f32x4 acc = zero;
#pragma unroll
            for (int ks = 0; ks < 4; ++ks)
                acc = __builtin_amdgcn_mfma_f32_16x16x32_bf16(qa[bb][m][ks], nb[ks], acc, 0, 0, 0);
#pragma unroll
            for (int r = 0; r < 4; ++r) {  // rowmax over s within 16-lane group
                float v = acc[r];
                v = fmaxf(v, __shfl_xor(v, 1));
                v = fmaxf(v, __shfl_xor(v, 2));
                v = fmaxf(v, __shfl_xor(v, 4));
                v = fmaxf(v, __shfl_xor(v, 8));
                if ((l & 15) == 0)
                    neg_part[(c * 64 + (b0 + bb)) * 32 + m * 16 + (l >> 4) * 4 + r] = v;
            }
        }
    }

    // Normalize vmcnt to exactly 0 so the counted scheme below is exact.
    asm volatile("s_waitcnt vmcnt(0) lgkmcnt(0)" ::: "memory");
    __builtin_amdgcn_sched_barrier(0);

    // DMA-stage chunk K into ring slot K&3: 512 threads x 2 issues x 16B,
    // linear (wave-uniform base + lane*16; fragment layout already linear).
#define STAGE(K)                                                                 \
    {                                                                            \
        const short* _s = dbase + (K) * 8192 + t * 8;                            \
        short* _d = &lds[(K) & 3][t * 8];                                        \
        _Pragma("unroll") for (int i = 0; i < 2; ++i)                            \
            __builtin_amdgcn_global_load_lds(                                    \
                (const __attribute__((address_space(1))) void*)(_s + i * 4096),  \
                (__attribute__((address_space(3))) void*)(_d + i * 4096),        \
                16, 0, 0);                                                       \
    }

    STAGE(0) STAGE(1) STAGE(2)  // 6 loads/thread in flight

    f32x4 vmax[2][2];
#pragma unroll
    for (int bb = 0; bb < 2; ++bb)
#pragma unroll
        for (int m = 0; m < 2; ++m)
#pragma unroll
            for (int r = 0; r < 4; ++r) vmax[bb][m][r] = -INFINITY;

    for (int ch = 0; ch < 16; ++ch) {
        // chunk ch resident when <= 2 chunks (4 loads) remain outstanding
        if (ch <= 13) {
            asm volatile("s_waitcnt vmcnt(4)" ::: "memory");
        } else if (ch == 14) {
            asm volatile("s_waitcnt vmcnt(2)" ::: "memory");
        } else {
            asm volatile("s_waitcnt vmcnt(0)" ::: "memory");
        }
        __builtin_amdgcn_sched_barrier(0);
        __builtin_amdgcn_s_barrier();  // chunk ch resident; slot (ch+3)&3 free
        if (ch + 3 < 16) STAGE(ch + 3)

        const short* buf = &lds[ch & 3][0];
#pragma unroll
        for (int ss = 0; ss < 4; ++ss) {
            short8 bf[4];
#pragma unroll
            for (int ks = 0; ks < 4; ++ks)
                bf[ks] = *(const short8*)(buf + ((ss * 4 + ks) * 64 + l) * 8);
            __builtin_amdgcn_s_setprio(1);
#pragma unroll
            for (int bb = 0; bb < 2; ++bb)
#pragma unroll
                for (int m = 0; m < 2; ++m) {
                    f32x4 acc = zero;
#pragma unroll
                    for (int ks = 0; ks < 4; ++ks)
                        acc = __builtin_amdgcn_mfma_f32_16x16x32_bf16(qa[bb][m][ks], bf[ks], acc, 0, 0, 0);
#pragma unroll
                    for (int r = 0; r < 4; ++r)
                        vmax[bb][m][r] = fmaxf(vmax[bb][m][r], acc[r]);
                }
            __builtin_amdgcn_s_setprio(0);
        }
    }
#undef STAGE

    // per-n rowmax -> score_part[(c*64 + b)*32 + n]
#pragma unroll
    for (int bb = 0; bb < 2; ++bb)
#pragma unroll
        for (int m = 0; m < 2; ++m)
#pragma unroll
            for (int r = 0; r < 4; ++r) {
                float v = vmax[bb][m][r];
                v = fmaxf(v, __shfl_xor(v, 1));
                v = fmaxf(v, __shfl_xor(v, 2));
                v = fmaxf(v, __shfl_xor(v, 4));
                v = fmaxf(v, __shfl_xor(v, 8));
                if ((l & 15) == 0)
                    score_part[((c * 64) + (b0 + bb)) * 32 + m * 16 + (l >> 4) * 4 + r] = v;
            }
}

// Per-b: scores[b][c] = sum_n score_part (c = lane), reduce neg over c,
// CE + softplus -> bloss[b]. 64 blocks x 64 threads.
__global__ __launch_bounds__(64) void reduce_b(const float* __restrict__ score_part,
                                               const float* __restrict__ neg_part,
                                               const int* __restrict__ offp,
                                               float* __restrict__ bloss) {
    int b = blockIdx.x;
    int c = threadIdx.x;  // one wave
    const float4* p0 = (const float4*)(score_part + (c * 64 + b) * 32);
    float s = 0.f;
#pragma unroll
    for (int j = 0; j < 8; ++j) {
        float4 a = p0[j];
        s += a.x + a.y + a.z + a.w;
    }
    // neg: elementwise max over c of neg_part[c][b][n], then sum over n
    float v[32];
    {
        const float4* np = (const float4*)(neg_part + (c * 64 + b) * 32);
#pragma unroll
        for (int j = 0; j < 8; ++j) {
            float4 a = np[j];
            v[j * 4] = a.x; v[j * 4 + 1] = a.y; v[j * 4 + 2] = a.z; v[j * 4 + 3] = a.w;
        }
    }
#pragma unroll
    for (int off = 1; off < 64; off <<= 1)
#pragma unroll
        for (int j = 0; j < 32; ++j) v[j] = fmaxf(v[j], __shfl_xor(v[j], off));
    float negs = 0.f;
#pragma unroll
    for (int j = 0; j < 32; ++j) negs += v[j];

    const float invT = 50.0f;
    float m = s;
#pragma unroll
    for (int off = 1; off < 64; off <<= 1) m = fmaxf(m, __shfl_xor(m, off));
    float e = expf((s - m) * invT);
#pragma unroll
    for (int off = 1; off < 64; off <<= 1) e += __shfl_xor(e, off);
    float lse = m * invT + logf(e);
    int label = offp[0] + b;
    label = label < 0 ? 0 : (label > 63 ? 63 : label);
    float slabel = __shfl(s, label);
    float pos = __shfl(s, b);
    if (c == 0) {
        float x = (negs - pos) * invT;
        float sp = fmaxf(x, 0.f) + log1pf(expf(-fabsf(x)));
        bloss[b] = sp + lse - slabel * invT;
    }
}

__global__ __launch_bounds__(64) void final_sum(const float* __restrict__ bloss,
                                                float* __restrict__ out) {
    float v = bloss[threadIdx.x];
#pragma unroll
    for (int off = 1; off < 64; off <<= 1) v += __shfl_xor(v, off);
    if (threadIdx.x == 0) out[0] = v * (0.5f / 64.f);
}

extern "C" void kernel_launch(void* const* d_in, const int* in_sizes, int n_in,
                              void* d_out, int out_size, void* d_ws, size_t ws_size,
                              hipStream_t stream) {
    const float* q = (const float*)d_in[0];
    const float* dc = (const float*)d_in[1];
    const float* ng = (const float*)d_in[2];
    const int* offp = (const int*)d_in[3];
    float* out = (float*)d_out;

    // ws: qf 512KB @0 | df 16MB @0x80000 | neg_part 512KB @0x1080000 |
    //     score_part 512KB @0x1100000 | bloss @0x1180000
    char* ws = (char*)d_ws;
    short* qf = (short*)(ws);
    short* df = (short*)(ws + 0x80000);
    float* neg_part = (float*)(ws + 0x1080000);
    float* score_part = (float*)(ws + 0x1100000);
    float* bloss = (float*)(ws + 0x1180000);
    if (ws_size < 0x1180200) return;

    convert_qd<<<2112, 256, 0, stream>>>(q, dc, qf, df);
    maxsim_main<<<dim3(64, 4), 512, 0, stream>>>(qf, df, ng, score_part, neg_part);
    reduce_b<<<64, 64, 0, stream>>>(score_part, neg_part, offp, bloss);
    final_sum<<<1, 64, 0, stream>>>(bloss, out);
}

// Round 15
// 52.441 us; speedup vs baseline: 1.4643x; 1.0033x over previous
//
#include <hip/hip_runtime.h>
#include <hip/hip_bf16.h>
#include <math.h>

// Problem dims (fixed by reference): B=64, N=32, S=1024, D=128
#define NB 64
#define NTOK 32
#define NS 1024
#define ND 128

typedef __attribute__((ext_vector_type(8))) short short8;  // 8 x bf16
typedef __attribute__((ext_vector_type(4))) float f32x4;

__device__ __forceinline__ unsigned short f2bf(float x) {
    unsigned int u = __builtin_bit_cast(unsigned int, x);
    u += 0x7fffu + ((u >> 16) & 1u);  // round-to-nearest-even
    return (unsigned short)(u >> 16);
}

// RTNE pack; used for the once-read neg inline convert (same rounding as f2bf).
__device__ __forceinline__ short8 cvt8(float4 a, float4 b) {
    union { unsigned int u[4]; short8 s; } r;
    asm("v_cvt_pk_bf16_f32 %0, %1, %2" : "=v"(r.u[0]) : "v"(a.x), "v"(a.y));
    asm("v_cvt_pk_bf16_f32 %0, %1, %2" : "=v"(r.u[1]) : "v"(a.z), "v"(a.w));
    asm("v_cvt_pk_bf16_f32 %0, %1, %2" : "=v"(r.u[2]) : "v"(b.x), "v"(b.y));
    asm("v_cvt_pk_bf16_f32 %0, %1, %2" : "=v"(r.u[3]) : "v"(b.z), "v"(b.w));
    return r.s;
}

// Convert ONLY q + doc (reused many times; neg converted inline in maxsim).
// Tile = 16x128 fp32 -> fragment layout [tile][ks(4)][lane(64)][8] bf16;
// lane l = row (l&15), k = ks*32+8*(l>>4)+j. LDS-bounced, both sides coalesced.
__global__ __launch_bounds__(256) void convert_qd(const float* __restrict__ q,
                                                  const float* __restrict__ dc,
                                                  short* __restrict__ qf,
                                                  short* __restrict__ df) {
    __shared__ short lds[2][2048];
    int t = threadIdx.x;
    int row = t >> 4, g = t & 15;
    int slot = ((g >> 2) * 64 + (g & 3) * 16 + row);
#pragma unroll
    for (int half = 0; half < 2; ++half) {
        int tile = blockIdx.x * 2 + half;  // [0,128) q | [128,4224) doc
        const float* in = (tile < 128) ? q : dc;
        int rel = (tile < 128) ? tile : tile - 128;
        const float4* src = (const float4*)(in + (size_t)rel * 2048 + t * 8);
        float4 a = src[0], b = src[1];
        float f[8] = {a.x, a.y, a.z, a.w, b.x, b.y, b.z, b.w};
        short8 r;
#pragma unroll
        for (int j = 0; j < 8; ++j) r[j] = (short)f2bf(f[j]);
        *(short8*)(&lds[half][slot * 8]) = r;
    }
    __syncthreads();
#pragma unroll
    for (int half = 0; half < 2; ++half) {
        int tile = blockIdx.x * 2 + half;
        short* out = (tile < 128) ? qf : df;
        int rel = (tile < 128) ? tile : tile - 128;
        *(short8*)(out + (size_t)rel * 2048 + t * 8) = *(const short8*)(&lds[half][t * 8]);
    }
}

// T3+T4 maxsim, block-level B-reuse doubled: 8 waves (512 thr), 16 b's/block
// (still 2 b/wave -> qa = 64 VGPR, R11's proven no-spill register shape).
// Grid (c=64, bg=4) = 256 blocks = 1/CU: per-CU MFMA + LDS reads unchanged vs
// R11, DMA bytes and barrier count per CU HALVED. XCD = c%8; 4 blocks/slice
// co-XCD. 16 chunks x 64 doc rows (16KB); 4-deep LDS ring; 3 chunks of DMA in
// flight (2 loads/thread each); counted vmcnt, never 0 in steady state.
__global__ __launch_bounds__(512, 1) void maxsim_main(const short* __restrict__ qf,
                                                      const short* __restrict__ df,
                                                      const float* __restrict__ ng,
                                                      float* __restrict__ score_part,
                                                      float* __restrict__ neg_part) {
    int c = blockIdx.x;
    int bg = blockIdx.y;
    int t = threadIdx.x;
    int w = t >> 6, l = t & 63;
    int b0 = bg * 16 + w * 2;  // this wave: b0, b0+1

    __shared__ alignas(16) short lds[4][8192];  // 4 x 16KB ring
    const short* dbase = df + (size_t)c * (NS * ND);
    f32x4 zero = {0.f, 0.f, 0.f, 0.f};

    // q fragments: [bb][mtile][kstep] -> 64 VGPR
    short8 qa[2][2][4];
#pragma unroll
    for (int bb = 0; bb < 2; ++bb)
#pragma unroll
        for (int m = 0; m < 2; ++m)
#pragma unroll
            for (int ks = 0; ks < 4; ++ks)
                qa[bb][m][ks] =
                    *(const short8*)(qf + (((b0 + bb) * 2 + m) * 4 + ks) * 512 + l * 8);

    // fused neg partial: tile (b, s-chunk c) of q[b]·neg[b], fp32 read + inline cvt
#pragma unroll
    for (int bb = 0; bb < 2; ++bb) {
        const float* nt =
            ng + ((size_t)((b0 + bb) * 64 + c) * 16 + (l & 15)) * ND + 8 * (l >> 4);
        short8 nb[4];
#pragma unroll
        for (int ks = 0; ks < 4; ++ks) {
            const float* sp = nt + ks * 32;
            nb[ks] = cvt8(((const float4*)sp)[0], ((const float4*)sp)[1]);
        }
#pragma unroll
        for (int m = 0; m < 2; ++m) {
            f32x4 acc = zero;
#pragma unroll
            for (int ks = 0; ks < 4; ++ks)
                acc = __builtin_amdgcn_mfma_f32_16x16x32_bf16(qa[bb][m][ks], nb[ks], acc, 0, 0, 0);
#pragma unroll
            for (int r = 0; r < 4; ++r) {  // rowmax over s within 16-lane group
                float v = acc[r];
                v = fmaxf(v, __shfl_xor(v, 1));
                v = fmaxf(v, __shfl_xor(v, 2));
                v = fmaxf(v, __shfl_xor(v, 4));
                v = fmaxf(v, __shfl_xor(v, 8));
                if ((l & 15) == 0)
                    neg_part[(c * 64 + (b0 + bb)) * 32 + m * 16 + (l >> 4) * 4 + r] = v;
            }
        }
    }

    // Normalize vmcnt to exactly 0 so the counted scheme below is exact.
    asm volatile("s_waitcnt vmcnt(0) lgkmcnt(0)" ::: "memory");
    __builtin_amdgcn_sched_barrier(0);

    // DMA-stage chunk K into ring slot K&3: 512 threads x 2 issues x 16B,
    // linear (wave-uniform base + lane*16; fragment layout already linear).
#define STAGE(K)                                                                 \
    {                                                                            \
        const short* _s = dbase + (K) * 8192 + t * 8;                            \
        short* _d = &lds[(K) & 3][t * 8];                                        \
        _Pragma("unroll") for (int i = 0; i < 2; ++i)                            \
            __builtin_amdgcn_global_load_lds(                                    \
                (const __attribute__((address_space(1))) void*)(_s + i * 4096),  \
                (__attribute__((address_space(3))) void*)(_d + i * 4096),        \
                16, 0, 0);                                                       \
    }

    STAGE(0) STAGE(1) STAGE(2)  // 6 loads/thread in flight

    f32x4 vmax[2][2];
#pragma unroll
    for (int bb = 0; bb < 2; ++bb)
#pragma unroll
        for (int m = 0; m < 2; ++m)
#pragma unroll
            for (int r = 0; r < 4; ++r) vmax[bb][m][r] = -INFINITY;

    for (int ch = 0; ch < 16; ++ch) {
        // chunk ch resident when <= 2 chunks (4 loads) remain outstanding
        if (ch <= 13) {
            asm volatile("s_waitcnt vmcnt(4)" ::: "memory");
        } else if (ch == 14) {
            asm volatile("s_waitcnt vmcnt(2)" ::: "memory");
        } else {
            asm volatile("s_waitcnt vmcnt(0)" ::: "memory");
        }
        __builtin_amdgcn_sched_barrier(0);
        __builtin_amdgcn_s_barrier();  // chunk ch resident; slot (ch+3)&3 free
        if (ch + 3 < 16) STAGE(ch + 3)

        const short* buf = &lds[ch & 3][0];
#pragma unroll
        for (int ss = 0; ss < 4; ++ss) {
            short8 bf[4];
#pragma unroll
            for (int ks = 0; ks < 4; ++ks)
                bf[ks] = *(const short8*)(buf + ((ss * 4 + ks) * 64 + l) * 8);
            __builtin_amdgcn_s_setprio(1);
#pragma unroll
            for (int bb = 0; bb < 2; ++bb)
#pragma unroll
                for (int m = 0; m < 2; ++m) {
                    f32x4 acc = zero;
#pragma unroll
                    for (int ks = 0; ks < 4; ++ks)
                        acc = __builtin_amdgcn_mfma_f32_16x16x32_bf16(qa[bb][m][ks], bf[ks], acc, 0, 0, 0);
#pragma unroll
                    for (int r = 0; r < 4; ++r)
                        vmax[bb][m][r] = fmaxf(vmax[bb][m][r], acc[r]);
                }
            __builtin_amdgcn_s_setprio(0);
        }
    }
#undef STAGE

    // per-n rowmax -> score_part[(c*64 + b)*32 + n]
#pragma unroll
    for (int bb = 0; bb < 2; ++bb)
#pragma unroll
        for (int m = 0; m < 2; ++m)
#pragma unroll
            for (int r = 0; r < 4; ++r) {
                float v = vmax[bb][m][r];
                v = fmaxf(v, __shfl_xor(v, 1));
                v = fmaxf(v, __shfl_xor(v, 2));
                v = fmaxf(v, __shfl_xor(v, 4));
                v = fmaxf(v, __shfl_xor(v, 8));
                if ((l & 15) == 0)
                    score_part[((c * 64) + (b0 + bb)) * 32 + m * 16 + (l >> 4) * 4 + r] = v;
            }
}

// Per-b: scores[b][c] = sum_n score_part (c = lane), reduce neg over c,
// CE + softplus -> bloss[b]. 64 blocks x 64 threads.
__global__ __launch_bounds__(64) void reduce_b(const float* __restrict__ score_part,
                                               const float* __restrict__ neg_part,
                                               const int* __restrict__ offp,
                                               float* __restrict__ bloss) {
    int b = blockIdx.x;
    int c = threadIdx.x;  // one wave
    const float4* p0 = (const float4*)(score_part + (c * 64 + b) * 32);
    float s = 0.f;
#pragma unroll
    for (int j = 0; j < 8; ++j) {
        float4 a = p0[j];
        s += a.x + a.y + a.z + a.w;
    }
    // neg: elementwise max over c of neg_part[c][b][n], then sum over n
    float v[32];
    {
        const float4* np = (const float4*)(neg_part + (c * 64 + b) * 32);
#pragma unroll
        for (int j = 0; j < 8; ++j) {
            float4 a = np[j];
            v[j * 4] = a.x; v[j * 4 + 1] = a.y; v[j * 4 + 2] = a.z; v[j * 4 + 3] = a.w;
        }
    }
#pragma unroll
    for (int off = 1; off < 64; off <<= 1)
#pragma unroll
        for (int j = 0; j < 32; ++j) v[j] = fmaxf(v[j], __shfl_xor(v[j], off));
    float negs = 0.f;
#pragma unroll
    for (int j = 0; j < 32; ++j) negs += v[j];

    const float invT = 50.0f;
    float m = s;
#pragma unroll
    for (int off = 1; off < 64; off <<= 1) m = fmaxf(m, __shfl_xor(m, off));
    float e = expf((s - m) * invT);
#pragma unroll
    for (int off = 1; off < 64; off <<= 1) e += __shfl_xor(e, off);
    float lse = m * invT + logf(e);
    int label = offp[0] + b;
    label = label < 0 ? 0 : (label > 63 ? 63 : label);
    float slabel = __shfl(s, label);
    float pos = __shfl(s, b);
    if (c == 0) {
        float x = (negs - pos) * invT;
        float sp = fmaxf(x, 0.f) + log1pf(expf(-fabsf(x)));
        bloss[b] = sp + lse - slabel * invT;
    }
}

__global__ __launch_bounds__(64) void final_sum(const float* __restrict__ bloss,
                                                float* __restrict__ out) {
    float v = bloss[threadIdx.x];
#pragma unroll
    for (int off = 1; off < 64; off <<= 1) v += __shfl_xor(v, off);
    if (threadIdx.x == 0) out[0] = v * (0.5f / 64.f);
}

extern "C" void kernel_launch(void* const* d_in, const int* in_sizes, int n_in,
                              void* d_out, int out_size, void* d_ws, size_t ws_size,
                              hipStream_t stream) {
    const float* q = (const float*)d_in[0];
    const float* dc = (const float*)d_in[1];
    const float* ng = (const float*)d_in[2];
    const int* offp = (const int*)d_in[3];
    float* out = (float*)d_out;

    // ws: qf 512KB @0 | df 16MB @0x80000 | neg_part 512KB @0x1080000 |
    //     score_part 512KB @0x1100000 | bloss @0x1180000
    char* ws = (char*)d_ws;
    short* qf = (short*)(ws);
    short* df = (short*)(ws + 0x80000);
    float* neg_part = (float*)(ws + 0x1080000);
    float* score_part = (float*)(ws + 0x1100000);
    float* bloss = (float*)(ws + 0x1180000);
    if (ws_size < 0x1180200) return;

    convert_qd<<<2112, 256, 0, stream>>>(q, dc, qf, df);
    maxsim_main<<<dim3(64, 4), 512, 0, stream>>>(qf, df, ng, score_part, neg_part);
    reduce_b<<<64, 64, 0, stream>>>(score_part, neg_part, offp, bloss);
    final_sum<<<1, 64, 0, stream>>>(bloss, out);
}